// Round 7
// baseline (312.518 us; speedup 1.0000x reference)
//
#include <hip/hip_runtime.h>

// Problem constants (B=8, Tq=Tv=512, D=512, U=128)
constexpr int Bb = 8;
constexpr int Tq = 512;
constexpr int Tv = 512;
constexpr int Dd = 512;
constexpr int Uu = 128;
constexpr float C2LOG2E = 2.88539008177792681f;   // 2*log2(e)
constexpr float LOG2E   = 1.44269504088896341f;

// ---------------------------------------------------------------------------
// Kernel A: projections, 8 rows/block, 256 threads, 1024 blocks. NO LDS:
// x rows are read with wave-uniform addresses (scalar-cache broadcast), W
// per-lane coalesced. Thread: u = t&127, rg = t>>7 -> rows rg*4..rg*4+3.
//   q half -> qf2[row][u] (row-major), k half -> kT[b][u][j] (transposed).
// Both premultiplied by 2*log2e so the score exp2 argument is one add.
// ---------------------------------------------------------------------------
__global__ __launch_bounds__(256) void proj_kernel(
    const float* __restrict__ query,
    const float* __restrict__ key,
    const float* __restrict__ Wa,
    const float* __restrict__ Ua,
    float* __restrict__ qf2, float* __restrict__ kT)
{
    const int R    = blockIdx.x * 8;               // 0..8191
    const bool isQ = R < Bb * Tq;
    const float* __restrict__ src = isQ ? query : key;
    const float* __restrict__ W   = isQ ? Wa : Ua;
    const int Rloc = isQ ? R : R - Bb * Tq;        // 0..4095

    const int t  = threadIdx.x;
    const int u  = t & 127;
    const int rg = t >> 7;                         // 0/1 (wave-uniform)
    const float* __restrict__ xr = src + (size_t)(Rloc + rg * 4) * Dd; // uniform
    const float* __restrict__ Wu = W + u;
    float acc[4] = {0, 0, 0, 0};

#pragma unroll 2
    for (int d4 = 0; d4 < Dd / 4; ++d4) {
        const int d = d4 * 4;
        const float w0 = Wu[(size_t)(d + 0) * Uu];
        const float w1 = Wu[(size_t)(d + 1) * Uu];
        const float w2 = Wu[(size_t)(d + 2) * Uu];
        const float w3 = Wu[(size_t)(d + 3) * Uu];
#pragma unroll
        for (int k = 0; k < 4; ++k) {
            const float4 xv = *reinterpret_cast<const float4*>(xr + (size_t)k * Dd + d);
            acc[k] = fmaf(xv.x, w0, acc[k]);
            acc[k] = fmaf(xv.y, w1, acc[k]);
            acc[k] = fmaf(xv.z, w2, acc[k]);
            acc[k] = fmaf(xv.w, w3, acc[k]);
        }
    }

    if (isQ) {
#pragma unroll
        for (int k = 0; k < 4; ++k)
            qf2[(size_t)(Rloc + rg * 4 + k) * Uu + u] = C2LOG2E * acc[k];
    } else {
        const int b  = Rloc >> 9;
        const int j0 = (Rloc & 511) + rg * 4;
        float4 o;
        o.x = C2LOG2E * acc[0]; o.y = C2LOG2E * acc[1];
        o.z = C2LOG2E * acc[2]; o.w = C2LOG2E * acc[3];
        *reinterpret_cast<float4*>(kT + (size_t)b * Uu * Tv + (size_t)u * Tv + j0) = o;
    }
}

// ---------------------------------------------------------------------------
// Kernel B: attention, 8 query rows/block, 1024 threads (16 waves), 512 blocks
// -> 2 blocks/CU = 32 waves/CU (100% occupancy cap).
//   score : j = t&511, ih = t>>9 -> rows ih*4..ih*4+3.  q/scale via
//           wave-uniform (scalar) loads, k coalesced per-lane.
//           w[i][j] = mask ? -2*sum_u scale_u*rcp(1+exp2(q2+k2)) : -1e9
//           (the +sum(scale) shift is dropped: softmax is shift-invariant)
//   softmax: 16 waves; wave wv -> row wv>>1, half wv&1; 2-stage LDS combine.
//   context: ti = t>>7 -> row ti; td = t&127 -> d = 4*td..+3.
// ---------------------------------------------------------------------------
__global__ __launch_bounds__(1024, 8) void attn_kernel(
    const float* __restrict__ qf2, const float* __restrict__ kT,
    const float* __restrict__ value,
    const int* __restrict__ mask,
    const float* __restrict__ scale,
    float* __restrict__ out)
{
    const int r0 = blockIdx.x * 8;            // first query row (0..4095)
    const int b  = r0 >> 9;
    const int t  = threadIdx.x;               // 0..1023

    __shared__ float w[8 * Tv];               // 16 KB
    __shared__ float pmax[16];
    __shared__ float psum[16];

    // ---- scores ----
    const int j  = t & 511;
    const int ih = t >> 9;                    // 0/1 (wave-uniform)
    const int mk = mask[b * Tv + j];
    const float* __restrict__ kb = kT + (size_t)b * Uu * Tv + j;
    const float* __restrict__ qb = qf2 + (size_t)(r0 + ih * 4) * Uu;  // uniform
    float acc[4] = {0, 0, 0, 0};

#pragma unroll 2
    for (int u4 = 0; u4 < Uu / 4; ++u4) {
        const float kx = kb[(size_t)(u4 * 4 + 0) * Tv];
        const float ky = kb[(size_t)(u4 * 4 + 1) * Tv];
        const float kz = kb[(size_t)(u4 * 4 + 2) * Tv];
        const float kw = kb[(size_t)(u4 * 4 + 3) * Tv];
        const float4 sv = *reinterpret_cast<const float4*>(scale + u4 * 4); // uniform
#pragma unroll
        for (int i = 0; i < 4; ++i) {
            const float4 qv = *reinterpret_cast<const float4*>(qb + i * Uu + u4 * 4); // uniform
            float e0 = __builtin_amdgcn_exp2f(qv.x + kx);
            float e1 = __builtin_amdgcn_exp2f(qv.y + ky);
            float e2 = __builtin_amdgcn_exp2f(qv.z + kz);
            float e3 = __builtin_amdgcn_exp2f(qv.w + kw);
            acc[i] = fmaf(sv.x, __builtin_amdgcn_rcpf(e0 + 1.f), acc[i]);
            acc[i] = fmaf(sv.y, __builtin_amdgcn_rcpf(e1 + 1.f), acc[i]);
            acc[i] = fmaf(sv.z, __builtin_amdgcn_rcpf(e2 + 1.f), acc[i]);
            acc[i] = fmaf(sv.w, __builtin_amdgcn_rcpf(e3 + 1.f), acc[i]);
        }
    }
#pragma unroll
    for (int i = 0; i < 4; ++i)
        w[(ih * 4 + i) * Tv + j] = mk ? (-2.f * acc[i]) : -1e9f;
    __syncthreads();

    // ---- softmax: wave wv -> row wv>>1, column half wv&1 ----
    {
        const int wv = t >> 6, ln = t & 63;
        const int row = wv >> 1, half = wv & 1;
        float* __restrict__ rw = w + row * Tv + half * 256;
        float vals[4];
        float m = -3e38f;
#pragma unroll
        for (int c = 0; c < 4; ++c) { vals[c] = rw[ln + 64 * c]; m = fmaxf(m, vals[c]); }
#pragma unroll
        for (int off = 32; off; off >>= 1) m = fmaxf(m, __shfl_xor(m, off, 64));
        if (ln == 0) pmax[wv] = m;
        __syncthreads();
        m = fmaxf(pmax[row * 2], pmax[row * 2 + 1]);
        float sum = 0.f;
#pragma unroll
        for (int c = 0; c < 4; ++c) {
            float e = __builtin_amdgcn_exp2f((vals[c] - m) * LOG2E);
            rw[ln + 64 * c] = e;
            sum += e;
        }
#pragma unroll
        for (int off = 32; off; off >>= 1) sum += __shfl_xor(sum, off, 64);
        if (ln == 0) psum[wv] = sum;
    }
    __syncthreads();

    // ---- context: row ti, 4 d's per thread ----
    const int ti = t >> 7;                 // 0..7 (wave-uniform)
    const int td = t & 127;
    const int d0 = td * 4;
    const float inv = 1.0f / (psum[ti * 2] + psum[ti * 2 + 1]);
    const float* __restrict__ vb = value + (size_t)b * Tv * Dd + d0;
    const float* __restrict__ wr = w + ti * Tv;
    float4 a = {0, 0, 0, 0};
#pragma unroll 2
    for (int j4 = 0; j4 < Tv / 4; ++j4) {
        const float4 wq = *reinterpret_cast<const float4*>(wr + j4 * 4);  // LDS broadcast
        const float4 v0 = *reinterpret_cast<const float4*>(vb + (size_t)(j4 * 4 + 0) * Dd);
        const float4 v1 = *reinterpret_cast<const float4*>(vb + (size_t)(j4 * 4 + 1) * Dd);
        const float4 v2 = *reinterpret_cast<const float4*>(vb + (size_t)(j4 * 4 + 2) * Dd);
        const float4 v3 = *reinterpret_cast<const float4*>(vb + (size_t)(j4 * 4 + 3) * Dd);
        a.x = fmaf(wq.x, v0.x, a.x); a.y = fmaf(wq.x, v0.y, a.y);
        a.z = fmaf(wq.x, v0.z, a.z); a.w = fmaf(wq.x, v0.w, a.w);
        a.x = fmaf(wq.y, v1.x, a.x); a.y = fmaf(wq.y, v1.y, a.y);
        a.z = fmaf(wq.y, v1.z, a.z); a.w = fmaf(wq.y, v1.w, a.w);
        a.x = fmaf(wq.z, v2.x, a.x); a.y = fmaf(wq.z, v2.y, a.y);
        a.z = fmaf(wq.z, v2.z, a.z); a.w = fmaf(wq.z, v2.w, a.w);
        a.x = fmaf(wq.w, v3.x, a.x); a.y = fmaf(wq.w, v3.y, a.y);
        a.z = fmaf(wq.w, v3.z, a.z); a.w = fmaf(wq.w, v3.w, a.w);
    }
    float4 o;
    o.x = a.x * inv; o.y = a.y * inv; o.z = a.z * inv; o.w = a.w * inv;
    *reinterpret_cast<float4*>(out + (size_t)(r0 + ti) * Dd + d0) = o;
}

extern "C" void kernel_launch(void* const* d_in, const int* in_sizes, int n_in,
                              void* d_out, int out_size, void* d_ws, size_t ws_size,
                              hipStream_t stream)
{
    const float* query = (const float*)d_in[0];
    const float* key   = (const float*)d_in[1];
    const float* value = (const float*)d_in[2];
    const int*   mask  = (const int*)d_in[3];     // proven int32 (R2 bit-identical)
    const float* Wa    = (const float*)d_in[4];
    const float* Ua    = (const float*)d_in[5];
    const float* scale = (const float*)d_in[6];
    float* out = (float*)d_out;

    float* qf2 = (float*)d_ws;                    // [4096,128] = 2 MB (premult)
    float* kT  = qf2 + Bb * Tq * Uu;              // [8][128][512] = 2 MB (premult, transposed)

    proj_kernel<<<(2 * Bb * Tq) / 8, 256, 0, stream>>>(query, key, Wa, Ua, qf2, kT);
    attn_kernel<<<(Bb * Tq) / 8, 1024, 0, stream>>>(qf2, kT, value, mask, scale, out);
}

// Round 8
// 185.350 us; speedup vs baseline: 1.6861x; 1.6861x over previous
//
#include <hip/hip_runtime.h>

// Problem constants (B=8, Tq=Tv=512, D=512, U=128)
constexpr int Bb = 8;
constexpr int Tq = 512;
constexpr int Tv = 512;
constexpr int Dd = 512;
constexpr int Uu = 128;
constexpr float C2LOG2E = 2.88539008177792681f;   // 2*log2(e)
constexpr float LOG2E   = 1.44269504088896341f;

// ---------------------------------------------------------------------------
// Kernel A: projections, 8 rows/block, 256 threads, 1024 blocks (16 waves/CU).
// x staged in LDS (b128 broadcasts). Thread: u = t&127, rg = t>>7 -> rows
// rg*4..rg*4+3.  q half -> qf2[row][u] row-major (coalesced).  k half ->
// kT[b][u][j] via an LDS transpose tile so stores are line-packed.
// Both premultiplied by 2*log2e.
// ---------------------------------------------------------------------------
__global__ __launch_bounds__(256) void proj_kernel(
    const float* __restrict__ query,
    const float* __restrict__ key,
    const float* __restrict__ Wa,
    const float* __restrict__ Ua,
    float* __restrict__ qf2, float* __restrict__ kT)
{
    const int R    = blockIdx.x * 8;               // 0..8191
    const bool isQ = R < Bb * Tq;
    const float* __restrict__ src = isQ ? query : key;
    const float* __restrict__ W   = isQ ? Wa : Ua;
    const int Rloc = isQ ? R : R - Bb * Tq;        // 0..4095

    __shared__ float x[8 * Dd];                    // 16 KB
    __shared__ float kt[128 * 9];                  // 4.5 KB transpose tile (pad 9)
    const int t = threadIdx.x;

    {   // stage 8 rows: 1024 float4, 4 per thread, coalesced
        const float4* __restrict__ s4 =
            reinterpret_cast<const float4*>(src + (size_t)Rloc * Dd);
        float4* x4 = reinterpret_cast<float4*>(x);
#pragma unroll
        for (int m = 0; m < 4; ++m) x4[t + 256 * m] = s4[t + 256 * m];
    }
    __syncthreads();

    const int u  = t & 127;
    const int rg = t >> 7;                         // 0/1 -> rows rg*4..rg*4+3
    const float* __restrict__ Wu = W + u;
    float acc[4] = {0, 0, 0, 0};

#pragma unroll 2
    for (int d4 = 0; d4 < Dd / 4; ++d4) {
        const int d = d4 * 4;
        const float w0 = Wu[(size_t)(d + 0) * Uu];
        const float w1 = Wu[(size_t)(d + 1) * Uu];
        const float w2 = Wu[(size_t)(d + 2) * Uu];
        const float w3 = Wu[(size_t)(d + 3) * Uu];
#pragma unroll
        for (int k = 0; k < 4; ++k) {
            const float4 xv = *reinterpret_cast<const float4*>(x + (rg * 4 + k) * Dd + d);
            acc[k] = fmaf(xv.x, w0, acc[k]);
            acc[k] = fmaf(xv.y, w1, acc[k]);
            acc[k] = fmaf(xv.z, w2, acc[k]);
            acc[k] = fmaf(xv.w, w3, acc[k]);
        }
    }

    if (isQ) {
#pragma unroll
        for (int k = 0; k < 4; ++k)
            qf2[(size_t)(Rloc + rg * 4 + k) * Uu + u] = C2LOG2E * acc[k];
    } else {
        // write into transpose tile: kt[u][jj], jj = rg*4+k
#pragma unroll
        for (int k = 0; k < 4; ++k)
            kt[u * 9 + rg * 4 + k] = C2LOG2E * acc[k];
        __syncthreads();
        const int b  = Rloc >> 9;
        const int j0 = Rloc & 511;                 // 8-aligned
        float* __restrict__ kbase = kT + (size_t)b * Uu * Tv;
#pragma unroll
        for (int it = 0; it < 4; ++it) {
            const int idx = t + 256 * it;          // 0..1023
            const int uu  = idx >> 3;
            const int jj  = idx & 7;
            kbase[(size_t)uu * Tv + j0 + jj] = kt[uu * 9 + jj];
        }
    }
}

// ---------------------------------------------------------------------------
// Kernel B: attention, 8 query rows/block, 512 threads, 512 blocks.
//   score : thread t <-> key j=t; acc[8]; q2/s2 LDS broadcasts, kT coalesced.
//           w[i][j] = mask ? -2*sum_u scale_u*rcp(1+exp2(q2+k2)) : -1e9
//   softmax: wave wv -> row wv.
//   context: group g=t>>8 owns j in [g*256,(g+1)*256); c=t&255 -> d pair
//            d0=2c; all 8 rows in registers; partials combined via LDS.
// ---------------------------------------------------------------------------
__global__ __launch_bounds__(512) void attn_kernel(
    const float* __restrict__ qf2, const float* __restrict__ kT,
    const float* __restrict__ value,
    const int* __restrict__ mask,
    const float* __restrict__ scale,
    float* __restrict__ out)
{
    const int r0 = blockIdx.x * 8;            // first query row (0..4095)
    const int b  = r0 >> 9;
    const int t  = threadIdx.x;               // 0..511

    __shared__ float q2[8 * Uu];              // 4 KB
    __shared__ float s2[Uu];                  // 0.5 KB
    __shared__ float w[8 * Tv];               // 16 KB
    __shared__ float pbuf[8 * Dd / 2 * 2];    // 16 KB (group-1 partial context)
    __shared__ float inv8[8];

    const int j  = t;
    const int mk = mask[b * Tv + j];          // hoisted

    if (t < 256)
        reinterpret_cast<float4*>(q2)[t] =
            reinterpret_cast<const float4*>(qf2 + (size_t)r0 * Uu)[t];
    if (t >= 256 && t < 384) { const int u = t - 256; s2[u] = scale[u]; }
    __syncthreads();

    // ---- scores ----
    const float* __restrict__ kb = kT + (size_t)b * Uu * Tv + j;
    float acc[8] = {0,0,0,0,0,0,0,0};
#pragma unroll 2
    for (int u4 = 0; u4 < Uu / 4; ++u4) {
        const float kx = kb[(size_t)(u4 * 4 + 0) * Tv];
        const float ky = kb[(size_t)(u4 * 4 + 1) * Tv];
        const float kz = kb[(size_t)(u4 * 4 + 2) * Tv];
        const float kw = kb[(size_t)(u4 * 4 + 3) * Tv];
        const float4 sv = reinterpret_cast<const float4*>(s2)[u4];
#pragma unroll
        for (int i = 0; i < 8; ++i) {
            const float4 qv = *reinterpret_cast<const float4*>(q2 + i * Uu + u4 * 4);
            float e0 = __builtin_amdgcn_exp2f(qv.x + kx);
            float e1 = __builtin_amdgcn_exp2f(qv.y + ky);
            float e2 = __builtin_amdgcn_exp2f(qv.z + kz);
            float e3 = __builtin_amdgcn_exp2f(qv.w + kw);
            acc[i] = fmaf(sv.x, __builtin_amdgcn_rcpf(e0 + 1.f), acc[i]);
            acc[i] = fmaf(sv.y, __builtin_amdgcn_rcpf(e1 + 1.f), acc[i]);
            acc[i] = fmaf(sv.z, __builtin_amdgcn_rcpf(e2 + 1.f), acc[i]);
            acc[i] = fmaf(sv.w, __builtin_amdgcn_rcpf(e3 + 1.f), acc[i]);
        }
    }
#pragma unroll
    for (int i = 0; i < 8; ++i)
        w[i * Tv + j] = mk ? (-2.f * acc[i]) : -1e9f;
    __syncthreads();

    // ---- softmax: wave wv handles row wv ----
    {
        const int wv = t >> 6, ln = t & 63;
        float* __restrict__ row = w + wv * Tv;
        float vals[8];
        float m = -3e38f;
#pragma unroll
        for (int c = 0; c < 8; ++c) { vals[c] = row[ln + 64 * c]; m = fmaxf(m, vals[c]); }
#pragma unroll
        for (int off = 32; off; off >>= 1) m = fmaxf(m, __shfl_xor(m, off, 64));
        float sum = 0.f;
#pragma unroll
        for (int c = 0; c < 8; ++c) {
            float e = __builtin_amdgcn_exp2f((vals[c] - m) * LOG2E);
            row[ln + 64 * c] = e;
            sum += e;
        }
#pragma unroll
        for (int off = 32; off; off >>= 1) sum += __shfl_xor(sum, off, 64);
        if (ln == 0) inv8[wv] = 1.0f / sum;
    }
    __syncthreads();

    // ---- context: group g owns j-half, all 8 rows, d-pair per thread ----
    const int g  = t >> 8;                 // 0/1
    const int c  = t & 255;
    const int d0 = c * 2;
    const int jb = g * 256;
    const float* __restrict__ vb = value + (size_t)b * Tv * Dd + d0;
    float ax[8], ay[8];
#pragma unroll
    for (int i = 0; i < 8; ++i) { ax[i] = 0.f; ay[i] = 0.f; }

#pragma unroll 2
    for (int j4 = 0; j4 < 64; ++j4) {
        const int jj = jb + j4 * 4;
        const float2 v0 = *reinterpret_cast<const float2*>(vb + (size_t)(jj + 0) * Dd);
        const float2 v1 = *reinterpret_cast<const float2*>(vb + (size_t)(jj + 1) * Dd);
        const float2 v2 = *reinterpret_cast<const float2*>(vb + (size_t)(jj + 2) * Dd);
        const float2 v3 = *reinterpret_cast<const float2*>(vb + (size_t)(jj + 3) * Dd);
#pragma unroll
        for (int i = 0; i < 8; ++i) {
            const float4 wq = *reinterpret_cast<const float4*>(w + i * Tv + jj); // broadcast
            ax[i] = fmaf(wq.x, v0.x, ax[i]); ay[i] = fmaf(wq.x, v0.y, ay[i]);
            ax[i] = fmaf(wq.y, v1.x, ax[i]); ay[i] = fmaf(wq.y, v1.y, ay[i]);
            ax[i] = fmaf(wq.z, v2.x, ax[i]); ay[i] = fmaf(wq.z, v2.y, ay[i]);
            ax[i] = fmaf(wq.w, v3.x, ax[i]); ay[i] = fmaf(wq.w, v3.y, ay[i]);
        }
    }

    if (g == 1) {
#pragma unroll
        for (int i = 0; i < 8; ++i) {
            pbuf[i * Dd + d0]     = ax[i];
            pbuf[i * Dd + d0 + 1] = ay[i];
        }
    }
    __syncthreads();
    if (g == 0) {
#pragma unroll
        for (int i = 0; i < 8; ++i) {
            const float iv = inv8[i];
            float2 o;
            o.x = (ax[i] + pbuf[i * Dd + d0])     * iv;
            o.y = (ay[i] + pbuf[i * Dd + d0 + 1]) * iv;
            *reinterpret_cast<float2*>(out + (size_t)(r0 + i) * Dd + d0) = o;
        }
    }
}

extern "C" void kernel_launch(void* const* d_in, const int* in_sizes, int n_in,
                              void* d_out, int out_size, void* d_ws, size_t ws_size,
                              hipStream_t stream)
{
    const float* query = (const float*)d_in[0];
    const float* key   = (const float*)d_in[1];
    const float* value = (const float*)d_in[2];
    const int*   mask  = (const int*)d_in[3];     // proven int32 (R2 bit-identical)
    const float* Wa    = (const float*)d_in[4];
    const float* Ua    = (const float*)d_in[5];
    const float* scale = (const float*)d_in[6];
    float* out = (float*)d_out;

    float* qf2 = (float*)d_ws;                    // [4096,128] = 2 MB (premult)
    float* kT  = qf2 + Bb * Tq * Uu;              // [8][128][512] = 2 MB (premult, transposed)

    proj_kernel<<<(2 * Bb * Tq) / 8, 256, 0, stream>>>(query, key, Wa, Ua, qf2, kT);
    attn_kernel<<<(Bb * Tq) / 8, 512, 0, stream>>>(qf2, kT, value, mask, scale, out);
}